// Round 12
// baseline (268.349 us; speedup 1.0000x reference)
//
#include <hip/hip_runtime.h>
#include <math.h>

// Problem constants
//  B=8, CTX=512, N_FRAMES=512, IN_DIM=1024, ST_DIM=128, HOP=512, N_SAMPLES=262144
//  HD=32, HL=16
// Scan parallelization: T=8 frames/chunk, C=64 chunks.
// 11 launches: megabuild, proj, projD, powers x3, ec, combine, pass2,
// Y(->YT), ola, conv(softmax+Toeplitz fused).
// This round: grid-barrier powers fusion REVERTED (spin barrier cost ~55us —
// cross-XCD atomic polls); kept MpowT transposed powers + row-contiguous
// ec/pass2/combine. GEMM stays r7 reg-staged dbuf.

typedef __attribute__((ext_vector_type(8))) short bfrag;   // 8 bf16 = 4 VGPRs
typedef __attribute__((ext_vector_type(4))) float f32x4;

__device__ inline unsigned short f2bf(float f) {
  unsigned int u = __float_as_uint(f);
  unsigned int r = (u + 0x7fff + ((u >> 16) & 1)) >> 16;   // RNE
  return (unsigned short)r;
}
__device__ inline float bf2f(unsigned short u) {
  return __uint_as_float(((unsigned int)u) << 16);
}

// ---------------- workspace layout (float offsets) ----------------
static const size_t OFF_WPT   = 139264;     // WpT bf16 [8][1024][512]
static const size_t OFF_WOT   = 2236416;    // WoT bf16 [8][1024][128]
static const size_t OFF_WDIT  = 2760704;    // WdiT bf16 [8][1152][1024]
static const size_t OFF_CTRLT = 7479296;    // ctrlT bf16 [8][512][512]
static const size_t OFF_PROJ  = 8527872;    // proj bf16 [8][512][1024]
static const size_t OFF_PROJD = 10625024;   // projD f32 [8][512][1152]
static const size_t OFF_S2    = 15343616;   // S2 bf16 [8][512][128]
static const size_t OFF_MPOW  = 15605760;   // f32 8*9*16384 (slot1 = Ws)
static const size_t OFF_EC    = 16785408;   // 65,536
static const size_t OFF_HC    = 16850944;   // 65,536
static const size_t OFF_Y     = 16916480;   // YT bf16 [8][1024][512]
static const size_t OFF_SIG   = 21110784;   // sigT bf16 [8][512][512]
static const size_t OFF_MPOWT = 22159360;   // f32 8*9*16384 (MkT[t][d] = Mk[d][t])

// ---------------- K1: mega-build (r7 form: float4 reads + batched LDS tile) ----------------
__global__ __launch_bounds__(256) void megabuild_kernel(
    const float* __restrict__ hv_p, const float* __restrict__ hv_s,
    const float* __restrict__ hv_i, const float* __restrict__ hv_o,
    const float* __restrict__ hv_d,
    const float* __restrict__ A_p, const float* __restrict__ A_s,
    const float* __restrict__ A_i, const float* __restrict__ A_o,
    const float* __restrict__ A_d,
    const float* __restrict__ B_p, const float* __restrict__ B_s,
    const float* __restrict__ B_i, const float* __restrict__ B_o,
    const float* __restrict__ B_d,
    const float* __restrict__ control,
    unsigned short* __restrict__ WpT, unsigned short* __restrict__ WoT,
    unsigned short* __restrict__ WdiT, float* __restrict__ Ws1,
    unsigned short* __restrict__ ctrlT) {
  __shared__ float ls[128];
  __shared__ unsigned short tile[8][32][36];   // [b][c][r] bf16, 18 KB
  __shared__ float ttile[32][33];
  const int blk = blockIdx.x;
  const int tid = threadIdx.x;

  if (blk >= 1808) {
    // ---- transpose+square role ----
    int z = blk - 1808;
    int b = z >> 8;
    int c0 = (z & 15) * 32, f0 = ((z >> 4) & 15) * 32;
    int tx = tid & 31, ty = tid >> 5;   // 32 x 8
    const float* inb = control + (size_t)b * 512 * 512;
    unsigned short* outb = ctrlT + (size_t)b * 512 * 512;
#pragma unroll
    for (int i = 0; i < 4; ++i) {
      float v = inb[(size_t)(c0 + ty + i * 8) * 512 + f0 + tx];
      ttile[ty + i * 8][tx] = v * v;
    }
    __syncthreads();
#pragma unroll
    for (int i = 0; i < 4; ++i)
      outb[(size_t)(f0 + ty + i * 8) * 512 + c0 + tx] = f2bf(ttile[tx][ty + i * 8]);
    return;
  }

  // ---- weight-build roles: select model ----
  const float* hv; const float* Am; const float* Bm;
  unsigned short* outw = nullptr; int R = 0, C = 0; size_t bstride = 0; int bx = 0, by = 0;
  int role;   // 0..3 = WT builds, 4 = Ws f32
  if (blk < 512)        { role = 0; hv = hv_p; Am = A_p; Bm = B_p; outw = WpT;  R = 512;  C = 1024; bstride = 524288;  bx = blk & 31;           by = blk >> 5; }
  else if (blk < 1536)  { role = 1; hv = hv_d; Am = A_d; Bm = B_d; outw = WdiT; R = 1024; C = 1024; bstride = 1179648; bx = (blk - 512) & 31;   by = (blk - 512) >> 5; }
  else if (blk < 1664)  { role = 2; hv = hv_i; Am = A_i; Bm = B_i; outw = WdiT + 1024 * 1024; R = 1024; C = 128; bstride = 1179648; bx = (blk - 1536) & 3; by = (blk - 1536) >> 2; }
  else if (blk < 1792)  { role = 3; hv = hv_o; Am = A_o; Bm = B_o; outw = WoT;  R = 128;  C = 1024; bstride = 131072;  bx = (blk - 1664) & 31;  by = (blk - 1664) >> 5; }
  else                  { role = 4; hv = hv_s; Am = A_s; Bm = B_s; }

  // latent slice for this model: ls[b*16+l] = sum_h hv[b*32+h] * Am[h*16+l]
  if (tid < 128) {
    int b = tid >> 4, l = tid & 15;
    float acc = 0.f;
#pragma unroll
    for (int h = 0; h < 32; ++h) acc = fmaf(hv[b * 32 + h], Am[h * 16 + l], acc);
    ls[tid] = acc;
  }

  if (role == 4) {
    __syncthreads();
    // Ws f32 -> Mpow slot 1 (bstride 9*16384)
    int e = ((blk - 1792) * 256 + tid) * 4;
    float4 v[16];
#pragma unroll
    for (int l = 0; l < 16; ++l)
      v[l] = *(const float4*)(Bm + (size_t)l * 16384 + e);
#pragma unroll 1
    for (int b = 0; b < 8; ++b) {
      float ax = 0.f, ay = 0.f, az = 0.f, aw = 0.f;
#pragma unroll
      for (int l = 0; l < 16; ++l) {
        float lv = ls[b * 16 + l];
        ax = fmaf(lv, v[l].x, ax);
        ay = fmaf(lv, v[l].y, ay);
        az = fmaf(lv, v[l].z, az);
        aw = fmaf(lv, v[l].w, aw);
      }
      *(float4*)(Ws1 + (size_t)b * 147456 + e) = make_float4(ax, ay, az, aw);
    }
    return;
  }

  // transposed bf16 W build: tile 32c x 32r, float4 reads, batched LDS transpose.
  const int rl = tid >> 3;            // 0..31
  const int c4 = (tid & 7) * 4;       // 0,4,...,28
  const size_t RC = (size_t)R * C;
  const float* Bp = Bm + (size_t)(by * 32 + rl) * C + bx * 32 + c4;
  float4 bm4[16];
#pragma unroll
  for (int l = 0; l < 16; ++l)
    bm4[l] = *(const float4*)(Bp + (size_t)l * RC);
  __syncthreads();   // ls ready

#pragma unroll 1
  for (int b = 0; b < 8; ++b) {
    float a0 = 0.f, a1 = 0.f, a2 = 0.f, a3 = 0.f;
#pragma unroll
    for (int l = 0; l < 16; ++l) {
      float lv = ls[b * 16 + l];
      a0 = fmaf(lv, bm4[l].x, a0);
      a1 = fmaf(lv, bm4[l].y, a1);
      a2 = fmaf(lv, bm4[l].z, a2);
      a3 = fmaf(lv, bm4[l].w, a3);
    }
    tile[b][c4 + 0][rl] = f2bf(a0);
    tile[b][c4 + 1][rl] = f2bf(a1);
    tile[b][c4 + 2][rl] = f2bf(a2);
    tile[b][c4 + 3][rl] = f2bf(a3);
  }
  __syncthreads();

  const int wc = tid >> 3, wrq = tid & 7;
  unsigned short* ob = outw + (size_t)(bx * 32 + wc) * R + by * 32 + wrq * 4;
#pragma unroll 1
  for (int b = 0; b < 8; ++b) {
    ushort4 v = *(const ushort4*)&tile[b][wc][wrq * 4];
    *(ushort4*)(ob + (size_t)b * bstride) = v;
  }
}

// ---------------- K4: bf16 MFMA GEMM, reg-staged double-buffered LDS (r7 form) ----------------
// C[b] = A[b] @ BT[b]^T.  A: [M][K] bf16.  BT: [N][K] bf16.  BM=BN=128, BK=32.
// OUTM: 0 = f32 [M][N]; 1 = bf16 [M][N]; 2 = bf16 [N][M] (YT).
template <int EPI, int OUTM>
__global__ __launch_bounds__(256) void mfma_gemm_kernel(
    const unsigned short* __restrict__ A,
    const unsigned short* __restrict__ BT,
    const float* __restrict__ D, int ldd,
    void* __restrict__ Cout,
    int M, int N, int K) {
  const int b = blockIdx.z;
  A  += (size_t)b * M * K;
  BT += (size_t)b * N * K;
  const int m0 = blockIdx.y * 128;
  const int n0 = blockIdx.x * 128;
  __shared__ __align__(16) unsigned short As[2][128][40];
  __shared__ __align__(16) unsigned short Bs[2][128][40];
  const int tid = threadIdx.x;
  const int lane = tid & 63, wave = tid >> 6;
  const int wr = (wave >> 1) * 64, wc = (wave & 1) * 64;
  const int l15 = lane & 15, g = lane >> 4;
  f32x4 acc[4][4];
#pragma unroll
  for (int i = 0; i < 4; ++i)
#pragma unroll
    for (int j = 0; j < 4; ++j)
#pragma unroll
      for (int r = 0; r < 4; ++r) acc[i][j][r] = 0.f;

  const int srow = tid >> 2, soct = tid & 3;
  const unsigned short* Ag = A + (size_t)(m0 + srow) * K + soct * 8;
  const unsigned short* Bg = BT + (size_t)(n0 + srow) * K + soct * 8;
  const size_t row64 = (size_t)64 * K;
  const int nt = K >> 5;

  bfrag av0 = *(const bfrag*)(Ag);
  bfrag av1 = *(const bfrag*)(Ag + row64);
  bfrag bv0 = *(const bfrag*)(Bg);
  bfrag bv1 = *(const bfrag*)(Bg + row64);

  int cur = 0;
#pragma unroll 1
  for (int t = 0; t < nt; ++t) {
    *(bfrag*)(&As[cur][srow][soct * 8]) = av0;
    *(bfrag*)(&As[cur][64 + srow][soct * 8]) = av1;
    *(bfrag*)(&Bs[cur][srow][soct * 8]) = bv0;
    *(bfrag*)(&Bs[cur][64 + srow][soct * 8]) = bv1;
    __syncthreads();
    if (t + 1 < nt) {
      const int k0 = (t + 1) << 5;
      av0 = *(const bfrag*)(Ag + k0);
      av1 = *(const bfrag*)(Ag + row64 + k0);
      bv0 = *(const bfrag*)(Bg + k0);
      bv1 = *(const bfrag*)(Bg + row64 + k0);
    }
    bfrag af[4], bf[4];
#pragma unroll
    for (int mi = 0; mi < 4; ++mi)
      af[mi] = *(const bfrag*)(&As[cur][wr + mi * 16 + l15][g * 8]);
#pragma unroll
    for (int nj = 0; nj < 4; ++nj)
      bf[nj] = *(const bfrag*)(&Bs[cur][wc + nj * 16 + l15][g * 8]);
#pragma unroll
    for (int mi = 0; mi < 4; ++mi)
#pragma unroll
      for (int nj = 0; nj < 4; ++nj)
        acc[mi][nj] = __builtin_amdgcn_mfma_f32_16x16x32_bf16(af[mi], bf[nj], acc[mi][nj], 0, 0, 0);
    cur ^= 1;
  }

  // epilogue: C/D frag mapping: col = l15, row = 4*g + r
  float* Cf = (float*)Cout + (size_t)b * M * N;
  unsigned short* Cb = (unsigned short*)Cout + (size_t)b * M * N;
  if (EPI) D += (size_t)b * M * ldd;
#pragma unroll
  for (int nj = 0; nj < 4; ++nj) {
    int n = n0 + wc + nj * 16 + l15;
    float win = 0.f;
    if (EPI) win = 0.5f - 0.5f * cosf(6.28318530717958647693f * (float)n / 1024.0f);
#pragma unroll
    for (int mi = 0; mi < 4; ++mi) {
      int mbase = m0 + wr + mi * 16 + 4 * g;
      float v[4];
#pragma unroll
      for (int r = 0; r < 4; ++r) {
        v[r] = acc[mi][nj][r];
        if (EPI) v[r] = (v[r] + D[(size_t)(mbase + r) * ldd + n]) * win;
      }
      if (OUTM == 2) {
        ushort4 o;
        o.x = f2bf(v[0]); o.y = f2bf(v[1]); o.z = f2bf(v[2]); o.w = f2bf(v[3]);
        *(ushort4*)(Cb + (size_t)n * M + mbase) = o;
      } else {
#pragma unroll
        for (int r = 0; r < 4; ++r) {
          if (OUTM == 1) Cb[(size_t)(mbase + r) * N + n] = f2bf(v[r]);
          else           Cf[(size_t)(mbase + r) * N + n] = v[r];
        }
      }
    }
  }
}

// ---------------- power step (device): C = A @ Bm, writes C and CT ----------------
__device__ inline void power_step_dev(const float* __restrict__ A,
                                      const float* __restrict__ Bm,
                                      float* __restrict__ C, float* __restrict__ CT,
                                      float (*As)[132], float (*Bs)[132], int tid) {
  int tx = tid & 15, ty = tid >> 4;
  float acc[8][8];
#pragma unroll
  for (int i = 0; i < 8; ++i)
#pragma unroll
    for (int j = 0; j < 8; ++j) acc[i][j] = 0.f;
  int ar = tid >> 1, ac = (tid & 1) * 8;
  int br = tid >> 4, bc = (tid & 15) * 8;
  for (int k0 = 0; k0 < 128; k0 += 16) {
    float4 a0 = *(const float4*)(A + (size_t)ar * 128 + k0 + ac);
    float4 a1 = *(const float4*)(A + (size_t)ar * 128 + k0 + ac + 4);
    float4 b0 = *(const float4*)(Bm + (size_t)(k0 + br) * 128 + bc);
    float4 b1 = *(const float4*)(Bm + (size_t)(k0 + br) * 128 + bc + 4);
    __syncthreads();
    As[ac + 0][ar] = a0.x; As[ac + 1][ar] = a0.y; As[ac + 2][ar] = a0.z; As[ac + 3][ar] = a0.w;
    As[ac + 4][ar] = a1.x; As[ac + 5][ar] = a1.y; As[ac + 6][ar] = a1.z; As[ac + 7][ar] = a1.w;
    *(float4*)(&Bs[br][bc]) = b0;
    *(float4*)(&Bs[br][bc + 4]) = b1;
    __syncthreads();
#pragma unroll
    for (int kk = 0; kk < 16; ++kk) {
      float4 av0 = *(const float4*)(&As[kk][ty * 8]);
      float4 av1 = *(const float4*)(&As[kk][ty * 8 + 4]);
      float4 bv0 = *(const float4*)(&Bs[kk][tx * 8]);
      float4 bv1 = *(const float4*)(&Bs[kk][tx * 8 + 4]);
      float aa[8] = {av0.x, av0.y, av0.z, av0.w, av1.x, av1.y, av1.z, av1.w};
      float bb[8] = {bv0.x, bv0.y, bv0.z, bv0.w, bv1.x, bv1.y, bv1.z, bv1.w};
#pragma unroll
      for (int i = 0; i < 8; ++i)
#pragma unroll
        for (int j = 0; j < 8; ++j) acc[i][j] = fmaf(aa[i], bb[j], acc[i][j]);
    }
  }
#pragma unroll
  for (int i = 0; i < 8; ++i) {
    *(float4*)(C + (size_t)(ty * 8 + i) * 128 + tx * 8) =
        make_float4(acc[i][0], acc[i][1], acc[i][2], acc[i][3]);
    *(float4*)(C + (size_t)(ty * 8 + i) * 128 + tx * 8 + 4) =
        make_float4(acc[i][4], acc[i][5], acc[i][6], acc[i][7]);
  }
#pragma unroll
  for (int j = 0; j < 8; ++j) {
    *(float4*)(CT + (size_t)(tx * 8 + j) * 128 + ty * 8) =
        make_float4(acc[0][j], acc[1][j], acc[2][j], acc[3][j]);
    *(float4*)(CT + (size_t)(tx * 8 + j) * 128 + ty * 8 + 4) =
        make_float4(acc[4][j], acc[5][j], acc[6][j], acc[7][j]);
  }
}

// ---------------- K5a: power step  M_{half+k} = M_k @ M_half (+CT); extra blocks do M1T ----------------
__global__ __launch_bounds__(256) void powers_kernel(
    float* __restrict__ Mpow, float* __restrict__ MpowT, int half) {
  __shared__ __align__(16) float As[16][132];
  __shared__ __align__(16) float Bs[16][132];
  const int z = blockIdx.x, tid = threadIdx.x;
  const int nwork = 8 * half;
  if (z < nwork) {
    int b = z / half, k = z - b * half + 1;
    power_step_dev(Mpow + ((size_t)b * 9 + k) * 16384,
                   Mpow + ((size_t)b * 9 + half) * 16384,
                   Mpow + ((size_t)b * 9 + half + k) * 16384,
                   MpowT + ((size_t)b * 9 + half + k) * 16384, As, Bs, tid);
  } else {
    // only reached when half==1 with grid 16: blocks 8..15 -> M1T[b]
    int b = z - nwork;
    const float* src = Mpow + ((size_t)b * 9 + 1) * 16384;
    float* dst = MpowT + ((size_t)b * 9 + 1) * 16384;
    float (*lt)[33] = (float(*)[33])As;
    int tx = tid & 31, ty = tid >> 5;
#pragma unroll 1
    for (int tl = 0; tl < 16; ++tl) {
      int r0 = (tl >> 2) * 32, c0 = (tl & 3) * 32;
      __syncthreads();
#pragma unroll
      for (int i = 0; i < 4; ++i)
        lt[ty + i * 8][tx] = src[(size_t)(r0 + ty + i * 8) * 128 + c0 + tx];
      __syncthreads();
#pragma unroll
      for (int i = 0; i < 4; ++i)
        dst[(size_t)(c0 + ty + i * 8) * 128 + r0 + tx] = lt[tx][ty + i * 8];
    }
  }
}

// ---------------- K5b: chunk aggregates (MpowT rows, contiguous) ----------------
__global__ __launch_bounds__(256) void ec_kernel(
    const float* __restrict__ MpowT, const float* __restrict__ PD,
    float* __restrict__ Ec) {
  int b = blockIdx.x >> 6, c = blockIdx.x & 63;
  int tid = threadIdx.x, t = tid & 127, dh = tid >> 7;
  __shared__ __align__(16) float Bus[7][128];
  __shared__ float red[128];
  const float* Bu = PD + (size_t)b * 512 * 1152 + 1024;
  for (int idx = tid; idx < 896; idx += 256)
    Bus[idx >> 7][idx & 127] = Bu[(size_t)(c * 8 + (idx >> 7)) * 1152 + (idx & 127)];
  __syncthreads();
  float acc = 0.f;
  const float* MbT = MpowT + (size_t)b * 9 * 16384;
  int d0 = dh * 64;
#pragma unroll
  for (int i = 0; i < 7; ++i) {
    const float* MkT = MbT + (size_t)(7 - i) * 16384 + (size_t)t * 128 + d0;
#pragma unroll
    for (int d4 = 0; d4 < 16; ++d4) {
      float4 mv = *(const float4*)(MkT + d4 * 4);
      acc = fmaf(Bus[i][d0 + d4 * 4 + 0], mv.x, acc);
      acc = fmaf(Bus[i][d0 + d4 * 4 + 1], mv.y, acc);
      acc = fmaf(Bus[i][d0 + d4 * 4 + 2], mv.z, acc);
      acc = fmaf(Bus[i][d0 + d4 * 4 + 3], mv.w, acc);
    }
  }
  if (dh == 1) red[t] = acc;
  __syncthreads();
  if (dh == 0) {
    float tot = acc + red[t] + Bu[(size_t)(c * 8 + 7) * 1152 + t];
    Ec[((size_t)b * 64 + c) * 128 + t] = tot;
  }
}

// ---------------- K5c: serial chunk combine (M8T rows; Ec staged in LDS) ----------------
__global__ __launch_bounds__(128) void combine_kernel(
    const float* __restrict__ MpowT, const float* __restrict__ Ec,
    float* __restrict__ Hc) {
  int b = blockIdx.x, t = threadIdx.x;
  float w[128];
  const float* M8T = MpowT + ((size_t)b * 9 + 8) * 16384 + (size_t)t * 128;
#pragma unroll
  for (int k = 0; k < 128; ++k) w[k] = M8T[k];
  __shared__ __align__(16) float ec_sh[64 * 128];
  const float* Ecb = Ec + (size_t)b * 8192;
#pragma unroll
  for (int i = 0; i < 16; ++i) {
    int idx = (t + i * 128) * 4;
    *(float4*)&ec_sh[idx] = *(const float4*)(Ecb + idx);
  }
  __shared__ __align__(16) float sh[2][128];
  sh[0][t] = 0.f;
  float* Hcb = Hc + (size_t)b * 8192;
  Hcb[t] = 0.f;
  __syncthreads();
  int cur = 0;
#pragma unroll 1
  for (int c = 0; c < 63; ++c) {
    float a0 = 0.f, a1 = 0.f, a2 = 0.f, a3 = 0.f;
#pragma unroll
    for (int k = 0; k < 128; k += 4) {
      float4 sv = *(const float4*)(&sh[cur][k]);
      a0 = fmaf(sv.x, w[k + 0], a0);
      a1 = fmaf(sv.y, w[k + 1], a1);
      a2 = fmaf(sv.z, w[k + 2], a2);
      a3 = fmaf(sv.w, w[k + 3], a3);
    }
    float hn = (a0 + a1) + (a2 + a3) + ec_sh[c * 128 + t];
    sh[cur ^ 1][t] = hn;
    Hcb[(c + 1) * 128 + t] = hn;
    __syncthreads();
    cur ^= 1;
  }
}

// ---------------- K5d: pass 2 (MpowT rows; S2 out in bf16) ----------------
__global__ __launch_bounds__(256) void pass2_kernel(
    const float* __restrict__ MpowT, const float* __restrict__ PD,
    const float* __restrict__ Hc, unsigned short* __restrict__ S2) {
  int b = blockIdx.x >> 6, c = blockIdx.x & 63;
  int tid = threadIdx.x, t = tid & 127, dh = tid >> 7;
  __shared__ __align__(16) float Xs[15][128];
  __shared__ __align__(16) float red[8][128];
  const float* Bu = PD + (size_t)b * 512 * 1152 + 1024;
  for (int idx = tid; idx < 15 * 128; idx += 256) {
    int rr = idx >> 7, cc = idx & 127;
    float v = 0.f;
    if (rr == 7) v = Hc[((size_t)b * 64 + c) * 128 + cc];
    else if (rr > 7) v = Bu[(size_t)(c * 8 + rr - 8) * 1152 + cc];
    Xs[rr][cc] = v;
  }
  __syncthreads();
  float acc[8];
#pragma unroll
  for (int j = 0; j < 8; ++j) acc[j] = 0.f;
  const float* MbT = MpowT + (size_t)b * 9 * 16384;
  int d0 = dh * 64;
#pragma unroll 1
  for (int k = 1; k <= 8; ++k) {
    const float* MkT = MbT + (size_t)k * 16384 + (size_t)t * 128;
    const int xbase = 8 - k;
#pragma unroll 4
    for (int d4 = 0; d4 < 16; ++d4) {
      int d = d0 + d4 * 4;
      float4 mv = *(const float4*)(MkT + d);
      float m0 = mv.x, m1 = mv.y, m2 = mv.z, m3 = mv.w;
#pragma unroll
      for (int j = 0; j < 8; ++j) {
        float4 xv = *(const float4*)(&Xs[xbase + j][d]);
        acc[j] = fmaf(xv.x, m0, acc[j]);
        acc[j] = fmaf(xv.y, m1, acc[j]);
        acc[j] = fmaf(xv.z, m2, acc[j]);
        acc[j] = fmaf(xv.w, m3, acc[j]);
      }
    }
  }
  if (dh == 1) {
#pragma unroll
    for (int j = 0; j < 8; ++j) red[j][t] = acc[j];
  }
  __syncthreads();
  if (dh == 0) {
    unsigned short* S2b = S2 + ((size_t)b * 512 + c * 8) * 128;
#pragma unroll
    for (int j = 0; j < 8; ++j)
      S2b[(size_t)j * 128 + t] = f2bf(acc[j] + red[j][t]);
  }
}

// ---------------- K7: OLA from YT -> sigT (both bf16, fully coalesced) ----------------
__global__ void ola_kernel(const unsigned short* __restrict__ YT,
                           unsigned short* __restrict__ sigT) {
  int idx = blockIdx.x * 256 + threadIdx.x;
  int b = idx >> 16;
  int rem = idx & 65535;
  int r = rem >> 7, p4 = (rem & 127) * 4;
  const unsigned short* Y1 = YT + (size_t)b * 524288 + (size_t)r * 512 + p4;
  const unsigned short* Y2 = YT + (size_t)b * 524288 + (size_t)(512 + r) * 512 + p4 - 1;
  ushort4 t1 = *(const ushort4*)Y1;
  float o0 = bf2f(t1.x), o1 = bf2f(t1.y), o2 = bf2f(t1.z), o3 = bf2f(t1.w);
  if (p4 > 0) o0 += bf2f(Y2[0]);
  o1 += bf2f(Y2[1]);
  o2 += bf2f(Y2[2]);
  o3 += bf2f(Y2[3]);
  ushort4 o;
  o.x = f2bf(o0); o.y = f2bf(o1); o.z = f2bf(o2); o.w = f2bf(o3);
  *(ushort4*)(sigT + (size_t)b * 262144 + (size_t)r * 512 + p4) = o;
}

// ---------------- K8: conv = softmax + Toeplitz-on-the-fly + triangular MFMA GEMM ----------------
__global__ __launch_bounds__(256) void conv_mfma_kernel(
    const float* __restrict__ times,
    const unsigned short* __restrict__ sigT,   // [B][512][512]
    float* __restrict__ out) {                 // [B][512*512]
  const int b = blockIdx.z;
  const int m0 = blockIdx.y * 128;
  const int n0 = blockIdx.x * 128;
  __shared__ unsigned short imp_bf[512];
  __shared__ float red[256];
  __shared__ __align__(16) unsigned short As[2][128][40];
  __shared__ __align__(16) unsigned short Bs[2][128][40];
  const int tid = threadIdx.x;

  float v0 = times[b * 512 + tid], v1 = times[b * 512 + 256 + tid];
  red[tid] = fmaxf(v0, v1);
  __syncthreads();
  for (int s = 128; s > 0; s >>= 1) {
    if (tid < s) red[tid] = fmaxf(red[tid], red[tid + s]);
    __syncthreads();
  }
  float mx = red[0];
  __syncthreads();
  float e0 = expf(v0 - mx), e1 = expf(v1 - mx);
  red[tid] = e0 + e1;
  __syncthreads();
  for (int s = 128; s > 0; s >>= 1) {
    if (tid < s) red[tid] += red[tid + s];
    __syncthreads();
  }
  float inv = 1.f / red[0];
  imp_bf[tid] = f2bf(e0 * inv);
  imp_bf[256 + tid] = f2bf(e1 * inv);
  __syncthreads();

  const int lane = tid & 63, wave = tid >> 6;
  const int wr = (wave >> 1) * 64, wc = (wave & 1) * 64;
  const int l15 = lane & 15, g = lane >> 4;
  f32x4 acc[4][4];
#pragma unroll
  for (int i = 0; i < 4; ++i)
#pragma unroll
    for (int j = 0; j < 4; ++j)
#pragma unroll
      for (int r = 0; r < 4; ++r) acc[i][j][r] = 0.f;

  const int srow = tid >> 2, soct = tid & 3;
  const int q0 = m0 + srow, q1 = m0 + 64 + srow;
  const unsigned short* Bg = sigT + (size_t)b * 262144 + (size_t)(n0 + srow) * 512 + soct * 8;
  const size_t row64 = (size_t)64 * 512;
  const int nt = (m0 + 128) >> 5;   // triangular K bound

  bfrag bv0 = *(const bfrag*)(Bg);
  bfrag bv1 = *(const bfrag*)(Bg + row64);

  int cur = 0;
#pragma unroll 1
  for (int t = 0; t < nt; ++t) {
    const int k0 = t << 5;
    bfrag av0, av1;
#pragma unroll
    for (int j = 0; j < 8; ++j) {
      int p = k0 + soct * 8 + j;
      av0[j] = (p <= q0) ? (short)imp_bf[q0 - p] : (short)0;
      av1[j] = (p <= q1) ? (short)imp_bf[q1 - p] : (short)0;
    }
    *(bfrag*)(&As[cur][srow][soct * 8]) = av0;
    *(bfrag*)(&As[cur][64 + srow][soct * 8]) = av1;
    *(bfrag*)(&Bs[cur][srow][soct * 8]) = bv0;
    *(bfrag*)(&Bs[cur][64 + srow][soct * 8]) = bv1;
    __syncthreads();
    if (t + 1 < nt) {
      const int kn = (t + 1) << 5;
      bv0 = *(const bfrag*)(Bg + kn);
      bv1 = *(const bfrag*)(Bg + row64 + kn);
    }
    bfrag af[4], bf[4];
#pragma unroll
    for (int mi = 0; mi < 4; ++mi)
      af[mi] = *(const bfrag*)(&As[cur][wr + mi * 16 + l15][g * 8]);
#pragma unroll
    for (int nj = 0; nj < 4; ++nj)
      bf[nj] = *(const bfrag*)(&Bs[cur][wc + nj * 16 + l15][g * 8]);
#pragma unroll
    for (int mi = 0; mi < 4; ++mi)
#pragma unroll
      for (int nj = 0; nj < 4; ++nj)
        acc[mi][nj] = __builtin_amdgcn_mfma_f32_16x16x32_bf16(af[mi], bf[nj], acc[mi][nj], 0, 0, 0);
    cur ^= 1;
  }

  float* Cf = out + (size_t)b * 262144;
#pragma unroll
  for (int nj = 0; nj < 4; ++nj) {
    int n = n0 + wc + nj * 16 + l15;
#pragma unroll
    for (int mi = 0; mi < 4; ++mi) {
      int mbase = m0 + wr + mi * 16 + 4 * g;
#pragma unroll
      for (int r = 0; r < 4; ++r)
        Cf[(size_t)(mbase + r) * 512 + n] = acc[mi][nj][r];
    }
  }
}

// ---------------- launcher ----------------
extern "C" void kernel_launch(void* const* d_in, const int* in_sizes, int n_in,
                              void* d_out, int out_size, void* d_ws, size_t ws_size,
                              hipStream_t stream) {
  const float* control   = (const float*)d_in[0];
  const float* state_hv  = (const float*)d_in[1];
  const float* output_hv = (const float*)d_in[2];
  const float* input_hv  = (const float*)d_in[3];
  const float* direct_hv = (const float*)d_in[4];
  const float* proj_hv   = (const float*)d_in[5];
  const float* times     = (const float*)d_in[6];
  const float* A_proj   = (const float*)d_in[7];
  const float* B_proj   = (const float*)d_in[8];
  const float* A_state  = (const float*)d_in[9];
  const float* B_state  = (const float*)d_in[10];
  const float* A_input  = (const float*)d_in[11];
  const float* B_input  = (const float*)d_in[12];
  const float* A_output = (const float*)d_in[13];
  const float* B_output = (const float*)d_in[14];
  const float* A_direct = (const float*)d_in[15];
  const float* B_direct = (const float*)d_in[16];

  float* ws = (float*)d_ws;
  unsigned short* WpT   = (unsigned short*)(ws + OFF_WPT);
  unsigned short* WoT   = (unsigned short*)(ws + OFF_WOT);
  unsigned short* WdiT  = (unsigned short*)(ws + OFF_WDIT);
  unsigned short* ctrlT = (unsigned short*)(ws + OFF_CTRLT);
  unsigned short* proj  = (unsigned short*)(ws + OFF_PROJ);
  float* projD = ws + OFF_PROJD;
  unsigned short* S2 = (unsigned short*)(ws + OFF_S2);
  float* Mpow  = ws + OFF_MPOW;
  float* MpowT = ws + OFF_MPOWT;
  float* Ec   = ws + OFF_EC;
  float* Hc   = ws + OFF_HC;
  unsigned short* YT   = (unsigned short*)(ws + OFF_Y);
  unsigned short* sigT = (unsigned short*)(ws + OFF_SIG);
  float* out  = (float*)d_out;

  // K1: all weight builds + latents + ctrl^2 transpose
  megabuild_kernel<<<3856, 256, 0, stream>>>(
      proj_hv, state_hv, input_hv, output_hv, direct_hv,
      A_proj, A_state, A_input, A_output, A_direct,
      B_proj, B_state, B_input, B_output, B_direct,
      control, WpT, WoT, WdiT, Mpow + 16384, ctrlT);

  // proj = ctrlT @ WpT^T  (M=512,N=1024,K=512) -> bf16
  mfma_gemm_kernel<0, 1><<<dim3(8, 4, 8), 256, 0, stream>>>(
      ctrlT, WpT, nullptr, 0, proj, 512, 1024, 512);

  // projD = proj @ WdiT^T  (M=512,N=1152,K=1024) -> f32
  mfma_gemm_kernel<0, 0><<<dim3(9, 4, 8), 256, 0, stream>>>(
      proj, WdiT, nullptr, 0, projD, 512, 1152, 1024);

  // powers: 3 launches; first also produces M1T (blocks 8..15)
  powers_kernel<<<16, 256, 0, stream>>>(Mpow, MpowT, 1);   // M2 (+T), M1T
  powers_kernel<<<16, 256, 0, stream>>>(Mpow, MpowT, 2);   // M3,M4 (+T)
  powers_kernel<<<32, 256, 0, stream>>>(Mpow, MpowT, 4);   // M5..M8 (+T)

  // chunked scan (MpowT row-contiguous reads)
  ec_kernel<<<512, 256, 0, stream>>>(MpowT, projD, Ec);
  combine_kernel<<<8, 128, 0, stream>>>(MpowT, Ec, Hc);
  pass2_kernel<<<512, 256, 0, stream>>>(MpowT, projD, Hc, S2);

  // YT = ((S2 @ WoT^T + direct) * win)^T  (M=512,N=1024,K=128) -> bf16 [N][M]
  mfma_gemm_kernel<1, 2><<<dim3(8, 4, 8), 256, 0, stream>>>(
      S2, WoT, projD, 1152, YT, 512, 1024, 128);

  // OLA: sigT[r][p] = YT[r][p] + YT[512+r][p-1]
  ola_kernel<<<2048, 256, 0, stream>>>(YT, sigT);

  // conv: softmax + Toeplitz-A on the fly + triangular MFMA GEMM -> out
  conv_mfma_kernel<<<dim3(4, 4, 8), 256, 0, stream>>>(times, sigT, out);
}

// Round 13
// 239.810 us; speedup vs baseline: 1.1190x; 1.1190x over previous
//
#include <hip/hip_runtime.h>
#include <math.h>

// Problem constants
//  B=8, CTX=512, N_FRAMES=512, IN_DIM=1024, ST_DIM=128, HOP=512, N_SAMPLES=262144
//  HD=32, HL=16
// Scan parallelization: T=8 frames/chunk, C=64 chunks.
// 12 launches: megabuild, proj, projD, powers x3, ec, combine, pass2, Y(->YT),
// ola, conv(softmax+Toeplitz fused).
// Round 13: full revert to the round-7 best (239.8us). MpowT experiment
// removed (scan reads Mpow with lane-coalesced Mk[d*128+t] — t is fast axis).

typedef __attribute__((ext_vector_type(8))) short bfrag;   // 8 bf16 = 4 VGPRs
typedef __attribute__((ext_vector_type(4))) float f32x4;

__device__ inline unsigned short f2bf(float f) {
  unsigned int u = __float_as_uint(f);
  unsigned int r = (u + 0x7fff + ((u >> 16) & 1)) >> 16;   // RNE
  return (unsigned short)r;
}
__device__ inline float bf2f(unsigned short u) {
  return __uint_as_float(((unsigned int)u) << 16);
}

// ---------------- workspace layout (float offsets) ----------------
static const size_t OFF_WPT   = 139264;     // WpT bf16 [8][1024][512]
static const size_t OFF_WOT   = 2236416;    // WoT bf16 [8][1024][128]
static const size_t OFF_WDIT  = 2760704;    // WdiT bf16 [8][1152][1024]
static const size_t OFF_CTRLT = 7479296;    // ctrlT bf16 [8][512][512]
static const size_t OFF_PROJ  = 8527872;    // proj bf16 [8][512][1024]
static const size_t OFF_PROJD = 10625024;   // projD f32 [8][512][1152]
static const size_t OFF_S2    = 15343616;   // S2 bf16 [8][512][128]
static const size_t OFF_MPOW  = 15605760;   // f32 8*9*16384 (slot1 = Ws)
static const size_t OFF_EC    = 16785408;   // 65,536
static const size_t OFF_HC    = 16850944;   // 65,536
static const size_t OFF_Y     = 16916480;   // YT bf16 [8][1024][512]
static const size_t OFF_SIG   = 21110784;   // sigT bf16 [8][512][512]

// ---------------- K1: mega-build ----------------
// blocks [0,512)      WpT   (R=512,  C=1024)  model=proj
// blocks [512,1536)   WdT   (R=1024, C=1024)  model=direct
// blocks [1536,1664)  WiT   (R=1024, C=128)   model=input
// blocks [1664,1792)  WoT   (R=128,  C=1024)  model=output
// blocks [1792,1808)  Ws f32 -> Mpow slot 1   model=state
// blocks [1808,3856)  transpose_sq: ctrlT[b,f,c] = control[b,c,f]^2 (bf16)
__global__ __launch_bounds__(256) void megabuild_kernel(
    const float* __restrict__ hv_p, const float* __restrict__ hv_s,
    const float* __restrict__ hv_i, const float* __restrict__ hv_o,
    const float* __restrict__ hv_d,
    const float* __restrict__ A_p, const float* __restrict__ A_s,
    const float* __restrict__ A_i, const float* __restrict__ A_o,
    const float* __restrict__ A_d,
    const float* __restrict__ B_p, const float* __restrict__ B_s,
    const float* __restrict__ B_i, const float* __restrict__ B_o,
    const float* __restrict__ B_d,
    const float* __restrict__ control,
    unsigned short* __restrict__ WpT, unsigned short* __restrict__ WoT,
    unsigned short* __restrict__ WdiT, float* __restrict__ Ws1,
    unsigned short* __restrict__ ctrlT) {
  __shared__ float ls[128];
  __shared__ unsigned short tile[8][32][36];   // [b][c][r] bf16, 18 KB
  __shared__ float ttile[32][33];
  const int blk = blockIdx.x;
  const int tid = threadIdx.x;

  if (blk >= 1808) {
    // ---- transpose+square role ----
    int z = blk - 1808;
    int b = z >> 8;
    int c0 = (z & 15) * 32, f0 = ((z >> 4) & 15) * 32;
    int tx = tid & 31, ty = tid >> 5;   // 32 x 8
    const float* inb = control + (size_t)b * 512 * 512;
    unsigned short* outb = ctrlT + (size_t)b * 512 * 512;
#pragma unroll
    for (int i = 0; i < 4; ++i) {
      float v = inb[(size_t)(c0 + ty + i * 8) * 512 + f0 + tx];
      ttile[ty + i * 8][tx] = v * v;
    }
    __syncthreads();
#pragma unroll
    for (int i = 0; i < 4; ++i)
      outb[(size_t)(f0 + ty + i * 8) * 512 + c0 + tx] = f2bf(ttile[tx][ty + i * 8]);
    return;
  }

  // ---- weight-build roles: select model ----
  const float* hv; const float* Am; const float* Bm;
  unsigned short* outw = nullptr; int R = 0, C = 0; size_t bstride = 0; int bx = 0, by = 0;
  int role;   // 0..3 = WT builds, 4 = Ws f32
  if (blk < 512)        { role = 0; hv = hv_p; Am = A_p; Bm = B_p; outw = WpT;  R = 512;  C = 1024; bstride = 524288;  bx = blk & 31;           by = blk >> 5; }
  else if (blk < 1536)  { role = 1; hv = hv_d; Am = A_d; Bm = B_d; outw = WdiT; R = 1024; C = 1024; bstride = 1179648; bx = (blk - 512) & 31;   by = (blk - 512) >> 5; }
  else if (blk < 1664)  { role = 2; hv = hv_i; Am = A_i; Bm = B_i; outw = WdiT + 1024 * 1024; R = 1024; C = 128; bstride = 1179648; bx = (blk - 1536) & 3; by = (blk - 1536) >> 2; }
  else if (blk < 1792)  { role = 3; hv = hv_o; Am = A_o; Bm = B_o; outw = WoT;  R = 128;  C = 1024; bstride = 131072;  bx = (blk - 1664) & 31;  by = (blk - 1664) >> 5; }
  else                  { role = 4; hv = hv_s; Am = A_s; Bm = B_s; }

  // latent slice for this model: ls[b*16+l] = sum_h hv[b*32+h] * Am[h*16+l]
  if (tid < 128) {
    int b = tid >> 4, l = tid & 15;
    float acc = 0.f;
#pragma unroll
    for (int h = 0; h < 32; ++h) acc = fmaf(hv[b * 32 + h], Am[h * 16 + l], acc);
    ls[tid] = acc;
  }

  if (role == 4) {
    __syncthreads();
    // Ws f32 -> Mpow slot 1 (bstride 9*16384)
    int e = ((blk - 1792) * 256 + tid) * 4;
    float4 v[16];
#pragma unroll
    for (int l = 0; l < 16; ++l)
      v[l] = *(const float4*)(Bm + (size_t)l * 16384 + e);
#pragma unroll 1
    for (int b = 0; b < 8; ++b) {
      float ax = 0.f, ay = 0.f, az = 0.f, aw = 0.f;
#pragma unroll
      for (int l = 0; l < 16; ++l) {
        float lv = ls[b * 16 + l];
        ax = fmaf(lv, v[l].x, ax);
        ay = fmaf(lv, v[l].y, ay);
        az = fmaf(lv, v[l].z, az);
        aw = fmaf(lv, v[l].w, aw);
      }
      *(float4*)(Ws1 + (size_t)b * 147456 + e) = make_float4(ax, ay, az, aw);
    }
    return;
  }

  // transposed bf16 W build: tile 32c x 32r, float4 reads, batched LDS transpose.
  const int rl = tid >> 3;            // 0..31
  const int c4 = (tid & 7) * 4;       // 0,4,...,28
  const size_t RC = (size_t)R * C;
  const float* Bp = Bm + (size_t)(by * 32 + rl) * C + bx * 32 + c4;
  float4 bm4[16];
#pragma unroll
  for (int l = 0; l < 16; ++l)
    bm4[l] = *(const float4*)(Bp + (size_t)l * RC);
  __syncthreads();   // ls ready

#pragma unroll 1
  for (int b = 0; b < 8; ++b) {
    float a0 = 0.f, a1 = 0.f, a2 = 0.f, a3 = 0.f;
#pragma unroll
    for (int l = 0; l < 16; ++l) {
      float lv = ls[b * 16 + l];
      a0 = fmaf(lv, bm4[l].x, a0);
      a1 = fmaf(lv, bm4[l].y, a1);
      a2 = fmaf(lv, bm4[l].z, a2);
      a3 = fmaf(lv, bm4[l].w, a3);
    }
    tile[b][c4 + 0][rl] = f2bf(a0);
    tile[b][c4 + 1][rl] = f2bf(a1);
    tile[b][c4 + 2][rl] = f2bf(a2);
    tile[b][c4 + 3][rl] = f2bf(a3);
  }
  __syncthreads();

  // write role: 8 lanes cover one c-row (64B); wave writes 8 rows
  const int wc = tid >> 3, wrq = tid & 7;
  unsigned short* ob = outw + (size_t)(bx * 32 + wc) * R + by * 32 + wrq * 4;
#pragma unroll 1
  for (int b = 0; b < 8; ++b) {
    ushort4 v = *(const ushort4*)&tile[b][wc][wrq * 4];
    *(ushort4*)(ob + (size_t)b * bstride) = v;
  }
}

// ---------------- K4: bf16 MFMA GEMM, double-buffered LDS ----------------
// C[b] = A[b] @ BT[b]^T.  A: [M][K] bf16.  BT: [N][K] bf16.  BM=BN=128, BK=32.
// OUTM: 0 = f32 [M][N]; 1 = bf16 [M][N]; 2 = bf16 [N][M] (YT).
// EPI: v = (acc + D[m][n]) * win(n) before store.
template <int EPI, int OUTM>
__global__ __launch_bounds__(256) void mfma_gemm_kernel(
    const unsigned short* __restrict__ A,
    const unsigned short* __restrict__ BT,
    const float* __restrict__ D, int ldd,
    void* __restrict__ Cout,
    int M, int N, int K) {
  const int b = blockIdx.z;
  A  += (size_t)b * M * K;
  BT += (size_t)b * N * K;
  const int m0 = blockIdx.y * 128;
  const int n0 = blockIdx.x * 128;
  __shared__ __align__(16) unsigned short As[2][128][40];
  __shared__ __align__(16) unsigned short Bs[2][128][40];
  const int tid = threadIdx.x;
  const int lane = tid & 63, wave = tid >> 6;
  const int wr = (wave >> 1) * 64, wc = (wave & 1) * 64;
  const int l15 = lane & 15, g = lane >> 4;
  f32x4 acc[4][4];
#pragma unroll
  for (int i = 0; i < 4; ++i)
#pragma unroll
    for (int j = 0; j < 4; ++j)
#pragma unroll
      for (int r = 0; r < 4; ++r) acc[i][j][r] = 0.f;

  const int srow = tid >> 2, soct = tid & 3;
  const unsigned short* Ag = A + (size_t)(m0 + srow) * K + soct * 8;
  const unsigned short* Bg = BT + (size_t)(n0 + srow) * K + soct * 8;
  const size_t row64 = (size_t)64 * K;
  const int nt = K >> 5;

  bfrag av0 = *(const bfrag*)(Ag);
  bfrag av1 = *(const bfrag*)(Ag + row64);
  bfrag bv0 = *(const bfrag*)(Bg);
  bfrag bv1 = *(const bfrag*)(Bg + row64);

  int cur = 0;
#pragma unroll 1
  for (int t = 0; t < nt; ++t) {
    *(bfrag*)(&As[cur][srow][soct * 8]) = av0;
    *(bfrag*)(&As[cur][64 + srow][soct * 8]) = av1;
    *(bfrag*)(&Bs[cur][srow][soct * 8]) = bv0;
    *(bfrag*)(&Bs[cur][64 + srow][soct * 8]) = bv1;
    __syncthreads();
    if (t + 1 < nt) {
      const int k0 = (t + 1) << 5;
      av0 = *(const bfrag*)(Ag + k0);
      av1 = *(const bfrag*)(Ag + row64 + k0);
      bv0 = *(const bfrag*)(Bg + k0);
      bv1 = *(const bfrag*)(Bg + row64 + k0);
    }
    bfrag af[4], bf[4];
#pragma unroll
    for (int mi = 0; mi < 4; ++mi)
      af[mi] = *(const bfrag*)(&As[cur][wr + mi * 16 + l15][g * 8]);
#pragma unroll
    for (int nj = 0; nj < 4; ++nj)
      bf[nj] = *(const bfrag*)(&Bs[cur][wc + nj * 16 + l15][g * 8]);
#pragma unroll
    for (int mi = 0; mi < 4; ++mi)
#pragma unroll
      for (int nj = 0; nj < 4; ++nj)
        acc[mi][nj] = __builtin_amdgcn_mfma_f32_16x16x32_bf16(af[mi], bf[nj], acc[mi][nj], 0, 0, 0);
    cur ^= 1;
  }

  // epilogue: C/D frag mapping: col = l15, row = 4*g + r
  float* Cf = (float*)Cout + (size_t)b * M * N;
  unsigned short* Cb = (unsigned short*)Cout + (size_t)b * M * N;
  if (EPI) D += (size_t)b * M * ldd;
#pragma unroll
  for (int nj = 0; nj < 4; ++nj) {
    int n = n0 + wc + nj * 16 + l15;
    float win = 0.f;
    if (EPI) win = 0.5f - 0.5f * cosf(6.28318530717958647693f * (float)n / 1024.0f);
#pragma unroll
    for (int mi = 0; mi < 4; ++mi) {
      int mbase = m0 + wr + mi * 16 + 4 * g;
      float v[4];
#pragma unroll
      for (int r = 0; r < 4; ++r) {
        v[r] = acc[mi][nj][r];
        if (EPI) v[r] = (v[r] + D[(size_t)(mbase + r) * ldd + n]) * win;
      }
      if (OUTM == 2) {
        ushort4 o;
        o.x = f2bf(v[0]); o.y = f2bf(v[1]); o.z = f2bf(v[2]); o.w = f2bf(v[3]);
        *(ushort4*)(Cb + (size_t)n * M + mbase) = o;
      } else {
#pragma unroll
        for (int r = 0; r < 4; ++r) {
          if (OUTM == 1) Cb[(size_t)(mbase + r) * N + n] = f2bf(v[r]);
          else           Cf[(size_t)(mbase + r) * N + n] = v[r];
        }
      }
    }
  }
}

// ---------------- K5a: power step  M_{half+k} = M_k @ M_half ----------------
__global__ __launch_bounds__(256) void powers_kernel(float* __restrict__ Mpow, int half) {
  int z = blockIdx.x;
  int b = z / half, k = z - b * half + 1;
  const float* A = Mpow + ((size_t)b * 9 + k) * 16384;
  const float* Bm = Mpow + ((size_t)b * 9 + half) * 16384;
  float* C = Mpow + ((size_t)b * 9 + half + k) * 16384;
  __shared__ __align__(16) float As[16][132];
  __shared__ __align__(16) float Bs[16][132];
  int tid = threadIdx.x;
  int tx = tid & 15, ty = tid >> 4;
  float acc[8][8];
#pragma unroll
  for (int i = 0; i < 8; ++i)
#pragma unroll
    for (int j = 0; j < 8; ++j) acc[i][j] = 0.f;
  int ar = tid >> 1, ac = (tid & 1) * 8;
  int br = tid >> 4, bc = (tid & 15) * 8;
  for (int k0 = 0; k0 < 128; k0 += 16) {
    float4 a0 = *(const float4*)(A + (size_t)ar * 128 + k0 + ac);
    float4 a1 = *(const float4*)(A + (size_t)ar * 128 + k0 + ac + 4);
    float4 b0 = *(const float4*)(Bm + (size_t)(k0 + br) * 128 + bc);
    float4 b1 = *(const float4*)(Bm + (size_t)(k0 + br) * 128 + bc + 4);
    __syncthreads();
    As[ac + 0][ar] = a0.x; As[ac + 1][ar] = a0.y; As[ac + 2][ar] = a0.z; As[ac + 3][ar] = a0.w;
    As[ac + 4][ar] = a1.x; As[ac + 5][ar] = a1.y; As[ac + 6][ar] = a1.z; As[ac + 7][ar] = a1.w;
    *(float4*)(&Bs[br][bc]) = b0;
    *(float4*)(&Bs[br][bc + 4]) = b1;
    __syncthreads();
#pragma unroll
    for (int kk = 0; kk < 16; ++kk) {
      float4 av0 = *(const float4*)(&As[kk][ty * 8]);
      float4 av1 = *(const float4*)(&As[kk][ty * 8 + 4]);
      float4 bv0 = *(const float4*)(&Bs[kk][tx * 8]);
      float4 bv1 = *(const float4*)(&Bs[kk][tx * 8 + 4]);
      float aa[8] = {av0.x, av0.y, av0.z, av0.w, av1.x, av1.y, av1.z, av1.w};
      float bb[8] = {bv0.x, bv0.y, bv0.z, bv0.w, bv1.x, bv1.y, bv1.z, bv1.w};
#pragma unroll
      for (int i = 0; i < 8; ++i)
#pragma unroll
        for (int j = 0; j < 8; ++j) acc[i][j] = fmaf(aa[i], bb[j], acc[i][j]);
    }
  }
#pragma unroll
  for (int i = 0; i < 8; ++i) {
    *(float4*)(C + (size_t)(ty * 8 + i) * 128 + tx * 8) =
        make_float4(acc[i][0], acc[i][1], acc[i][2], acc[i][3]);
    *(float4*)(C + (size_t)(ty * 8 + i) * 128 + tx * 8 + 4) =
        make_float4(acc[i][4], acc[i][5], acc[i][6], acc[i][7]);
  }
}

// ---------------- K5b: chunk aggregates ----------------
__global__ __launch_bounds__(256) void ec_kernel(
    const float* __restrict__ Mpow, const float* __restrict__ PD,
    float* __restrict__ Ec) {
  int b = blockIdx.x >> 6, c = blockIdx.x & 63;
  int tid = threadIdx.x, t = tid & 127, dh = tid >> 7;
  __shared__ __align__(16) float Bus[7][128];
  __shared__ float red[128];
  const float* Bu = PD + (size_t)b * 512 * 1152 + 1024;
  for (int idx = tid; idx < 896; idx += 256)
    Bus[idx >> 7][idx & 127] = Bu[(size_t)(c * 8 + (idx >> 7)) * 1152 + (idx & 127)];
  __syncthreads();
  float acc = 0.f;
  const float* Mb = Mpow + (size_t)b * 9 * 16384;
  int d0 = dh * 64;
#pragma unroll
  for (int i = 0; i < 7; ++i) {
    const float* Mk = Mb + (size_t)(7 - i) * 16384 + t;
#pragma unroll 8
    for (int d = 0; d < 64; ++d)
      acc = fmaf(Bus[i][d0 + d], Mk[(size_t)(d0 + d) * 128], acc);
  }
  if (dh == 1) red[t] = acc;
  __syncthreads();
  if (dh == 0) {
    float tot = acc + red[t] + Bu[(size_t)(c * 8 + 7) * 1152 + t];
    Ec[((size_t)b * 64 + c) * 128 + t] = tot;
  }
}

// ---------------- K5c: serial chunk combine (Ec staged in LDS, dbuf state) ----------------
__global__ __launch_bounds__(128) void combine_kernel(
    const float* __restrict__ Mpow, const float* __restrict__ Ec,
    float* __restrict__ Hc) {
  int b = blockIdx.x, t = threadIdx.x;
  float w[128];
  const float* M8 = Mpow + ((size_t)b * 9 + 8) * 16384;
#pragma unroll
  for (int k = 0; k < 128; ++k) w[k] = M8[(size_t)k * 128 + t];
  __shared__ __align__(16) float ec_sh[64 * 128];
  const float* Ecb = Ec + (size_t)b * 8192;
#pragma unroll
  for (int i = 0; i < 16; ++i) {
    int idx = (t + i * 128) * 4;
    *(float4*)&ec_sh[idx] = *(const float4*)(Ecb + idx);
  }
  __shared__ __align__(16) float sh[2][128];
  sh[0][t] = 0.f;
  float* Hcb = Hc + (size_t)b * 8192;
  Hcb[t] = 0.f;
  __syncthreads();
  int cur = 0;
#pragma unroll 1
  for (int c = 0; c < 63; ++c) {
    float a0 = 0.f, a1 = 0.f, a2 = 0.f, a3 = 0.f;
#pragma unroll
    for (int k = 0; k < 128; k += 4) {
      float4 sv = *(const float4*)(&sh[cur][k]);
      a0 = fmaf(sv.x, w[k + 0], a0);
      a1 = fmaf(sv.y, w[k + 1], a1);
      a2 = fmaf(sv.z, w[k + 2], a2);
      a3 = fmaf(sv.w, w[k + 3], a3);
    }
    float hn = (a0 + a1) + (a2 + a3) + ec_sh[c * 128 + t];
    sh[cur ^ 1][t] = hn;
    Hcb[(c + 1) * 128 + t] = hn;
    __syncthreads();
    cur ^= 1;
  }
}

// ---------------- K5d: pass 2 (S2 out in bf16) ----------------
__global__ __launch_bounds__(256) void pass2_kernel(
    const float* __restrict__ Mpow, const float* __restrict__ PD,
    const float* __restrict__ Hc, unsigned short* __restrict__ S2) {
  int b = blockIdx.x >> 6, c = blockIdx.x & 63;
  int tid = threadIdx.x, t = tid & 127, dh = tid >> 7;
  __shared__ __align__(16) float Xs[15][128];
  __shared__ __align__(16) float red[8][128];
  const float* Bu = PD + (size_t)b * 512 * 1152 + 1024;
  for (int idx = tid; idx < 15 * 128; idx += 256) {
    int rr = idx >> 7, cc = idx & 127;
    float v = 0.f;
    if (rr == 7) v = Hc[((size_t)b * 64 + c) * 128 + cc];
    else if (rr > 7) v = Bu[(size_t)(c * 8 + rr - 8) * 1152 + cc];
    Xs[rr][cc] = v;
  }
  __syncthreads();
  float acc[8];
#pragma unroll
  for (int j = 0; j < 8; ++j) acc[j] = 0.f;
  const float* Mb = Mpow + (size_t)b * 9 * 16384;
  int d0 = dh * 64;
#pragma unroll 1
  for (int k = 1; k <= 8; ++k) {
    const float* Mk = Mb + (size_t)k * 16384 + t;
    const int xbase = 8 - k;
#pragma unroll 4
    for (int d4 = 0; d4 < 16; ++d4) {
      int d = d0 + d4 * 4;
      float m0 = Mk[(size_t)(d + 0) * 128];
      float m1 = Mk[(size_t)(d + 1) * 128];
      float m2 = Mk[(size_t)(d + 2) * 128];
      float m3 = Mk[(size_t)(d + 3) * 128];
#pragma unroll
      for (int j = 0; j < 8; ++j) {
        float4 xv = *(const float4*)(&Xs[xbase + j][d]);
        acc[j] = fmaf(xv.x, m0, acc[j]);
        acc[j] = fmaf(xv.y, m1, acc[j]);
        acc[j] = fmaf(xv.z, m2, acc[j]);
        acc[j] = fmaf(xv.w, m3, acc[j]);
      }
    }
  }
  if (dh == 1) {
#pragma unroll
    for (int j = 0; j < 8; ++j) red[j][t] = acc[j];
  }
  __syncthreads();
  if (dh == 0) {
    unsigned short* S2b = S2 + ((size_t)b * 512 + c * 8) * 128;
#pragma unroll
    for (int j = 0; j < 8; ++j)
      S2b[(size_t)j * 128 + t] = f2bf(acc[j] + red[j][t]);
  }
}

// ---------------- K7: OLA from YT -> sigT (both bf16, fully coalesced) ----------------
// sigT[b][r][p] = YT[b][r][p] + (p>0 ? YT[b][512+r][p-1] : 0)
__global__ void ola_kernel(const unsigned short* __restrict__ YT,
                           unsigned short* __restrict__ sigT) {
  int idx = blockIdx.x * 256 + threadIdx.x;   // 8*512*128 threads, 4 p's each
  int b = idx >> 16;
  int rem = idx & 65535;
  int r = rem >> 7, p4 = (rem & 127) * 4;
  const unsigned short* Y1 = YT + (size_t)b * 524288 + (size_t)r * 512 + p4;
  const unsigned short* Y2 = YT + (size_t)b * 524288 + (size_t)(512 + r) * 512 + p4 - 1;
  ushort4 t1 = *(const ushort4*)Y1;
  float o0 = bf2f(t1.x), o1 = bf2f(t1.y), o2 = bf2f(t1.z), o3 = bf2f(t1.w);
  if (p4 > 0) o0 += bf2f(Y2[0]);
  o1 += bf2f(Y2[1]);
  o2 += bf2f(Y2[2]);
  o3 += bf2f(Y2[3]);
  ushort4 o;
  o.x = f2bf(o0); o.y = f2bf(o1); o.z = f2bf(o2); o.w = f2bf(o3);
  *(ushort4*)(sigT + (size_t)b * 262144 + (size_t)r * 512 + p4) = o;
}

// ---------------- K8: conv = softmax + Toeplitz-on-the-fly + triangular MFMA GEMM ----------------
__global__ __launch_bounds__(256) void conv_mfma_kernel(
    const float* __restrict__ times,
    const unsigned short* __restrict__ sigT,   // [B][512][512]
    float* __restrict__ out) {                 // [B][512*512]
  const int b = blockIdx.z;
  const int m0 = blockIdx.y * 128;
  const int n0 = blockIdx.x * 128;
  __shared__ unsigned short imp_bf[512];
  __shared__ float red[256];
  __shared__ __align__(16) unsigned short As[2][128][40];
  __shared__ __align__(16) unsigned short Bs[2][128][40];
  const int tid = threadIdx.x;

  // softmax(times[b][0..511]) -> imp_bf (bf16)
  float v0 = times[b * 512 + tid], v1 = times[b * 512 + 256 + tid];
  red[tid] = fmaxf(v0, v1);
  __syncthreads();
  for (int s = 128; s > 0; s >>= 1) {
    if (tid < s) red[tid] = fmaxf(red[tid], red[tid + s]);
    __syncthreads();
  }
  float mx = red[0];
  __syncthreads();
  float e0 = expf(v0 - mx), e1 = expf(v1 - mx);
  red[tid] = e0 + e1;
  __syncthreads();
  for (int s = 128; s > 0; s >>= 1) {
    if (tid < s) red[tid] += red[tid + s];
    __syncthreads();
  }
  float inv = 1.f / red[0];
  imp_bf[tid] = f2bf(e0 * inv);
  imp_bf[256 + tid] = f2bf(e1 * inv);
  __syncthreads();

  const int lane = tid & 63, wave = tid >> 6;
  const int wr = (wave >> 1) * 64, wc = (wave & 1) * 64;
  const int l15 = lane & 15, g = lane >> 4;
  f32x4 acc[4][4];
#pragma unroll
  for (int i = 0; i < 4; ++i)
#pragma unroll
    for (int j = 0; j < 4; ++j)
#pragma unroll
      for (int r = 0; r < 4; ++r) acc[i][j][r] = 0.f;

  const int srow = tid >> 2, soct = tid & 3;
  const int q0 = m0 + srow, q1 = m0 + 64 + srow;
  const unsigned short* Bg = sigT + (size_t)b * 262144 + (size_t)(n0 + srow) * 512 + soct * 8;
  const size_t row64 = (size_t)64 * 512;
  const int nt = (m0 + 128) >> 5;   // triangular K bound

  bfrag bv0 = *(const bfrag*)(Bg);
  bfrag bv1 = *(const bfrag*)(Bg + row64);

  int cur = 0;
#pragma unroll 1
  for (int t = 0; t < nt; ++t) {
    const int k0 = t << 5;
    bfrag av0, av1;
#pragma unroll
    for (int j = 0; j < 8; ++j) {
      int p = k0 + soct * 8 + j;
      av0[j] = (p <= q0) ? (short)imp_bf[q0 - p] : (short)0;
      av1[j] = (p <= q1) ? (short)imp_bf[q1 - p] : (short)0;
    }
    *(bfrag*)(&As[cur][srow][soct * 8]) = av0;
    *(bfrag*)(&As[cur][64 + srow][soct * 8]) = av1;
    *(bfrag*)(&Bs[cur][srow][soct * 8]) = bv0;
    *(bfrag*)(&Bs[cur][64 + srow][soct * 8]) = bv1;
    __syncthreads();
    if (t + 1 < nt) {
      const int kn = (t + 1) << 5;
      bv0 = *(const bfrag*)(Bg + kn);
      bv1 = *(const bfrag*)(Bg + row64 + kn);
    }
    bfrag af[4], bf[4];
#pragma unroll
    for (int mi = 0; mi < 4; ++mi)
      af[mi] = *(const bfrag*)(&As[cur][wr + mi * 16 + l15][g * 8]);
#pragma unroll
    for (int nj = 0; nj < 4; ++nj)
      bf[nj] = *(const bfrag*)(&Bs[cur][wc + nj * 16 + l15][g * 8]);
#pragma unroll
    for (int mi = 0; mi < 4; ++mi)
#pragma unroll
      for (int nj = 0; nj < 4; ++nj)
        acc[mi][nj] = __builtin_amdgcn_mfma_f32_16x16x32_bf16(af[mi], bf[nj], acc[mi][nj], 0, 0, 0);
    cur ^= 1;
  }

  float* Cf = out + (size_t)b * 262144;
#pragma unroll
  for (int nj = 0; nj < 4; ++nj) {
    int n = n0 + wc + nj * 16 + l15;
#pragma unroll
    for (int mi = 0; mi < 4; ++mi) {
      int mbase = m0 + wr + mi * 16 + 4 * g;
#pragma unroll
      for (int r = 0; r < 4; ++r)
        Cf[(size_t)(mbase + r) * 512 + n] = acc[mi][nj][r];
    }
  }
}

// ---------------- launcher ----------------
extern "C" void kernel_launch(void* const* d_in, const int* in_sizes, int n_in,
                              void* d_out, int out_size, void* d_ws, size_t ws_size,
                              hipStream_t stream) {
  const float* control   = (const float*)d_in[0];
  const float* state_hv  = (const float*)d_in[1];
  const float* output_hv = (const float*)d_in[2];
  const float* input_hv  = (const float*)d_in[3];
  const float* direct_hv = (const float*)d_in[4];
  const float* proj_hv   = (const float*)d_in[5];
  const float* times     = (const float*)d_in[6];
  const float* A_proj   = (const float*)d_in[7];
  const float* B_proj   = (const float*)d_in[8];
  const float* A_state  = (const float*)d_in[9];
  const float* B_state  = (const float*)d_in[10];
  const float* A_input  = (const float*)d_in[11];
  const float* B_input  = (const float*)d_in[12];
  const float* A_output = (const float*)d_in[13];
  const float* B_output = (const float*)d_in[14];
  const float* A_direct = (const float*)d_in[15];
  const float* B_direct = (const float*)d_in[16];

  float* ws = (float*)d_ws;
  unsigned short* WpT   = (unsigned short*)(ws + OFF_WPT);
  unsigned short* WoT   = (unsigned short*)(ws + OFF_WOT);
  unsigned short* WdiT  = (unsigned short*)(ws + OFF_WDIT);
  unsigned short* ctrlT = (unsigned short*)(ws + OFF_CTRLT);
  unsigned short* proj  = (unsigned short*)(ws + OFF_PROJ);
  float* projD = ws + OFF_PROJD;
  unsigned short* S2 = (unsigned short*)(ws + OFF_S2);
  float* Mpow = ws + OFF_MPOW;
  float* Ec   = ws + OFF_EC;
  float* Hc   = ws + OFF_HC;
  unsigned short* YT   = (unsigned short*)(ws + OFF_Y);
  unsigned short* sigT = (unsigned short*)(ws + OFF_SIG);
  float* out  = (float*)d_out;

  // K1: all weight builds + latents + ctrl^2 transpose in one launch
  megabuild_kernel<<<3856, 256, 0, stream>>>(
      proj_hv, state_hv, input_hv, output_hv, direct_hv,
      A_proj, A_state, A_input, A_output, A_direct,
      B_proj, B_state, B_input, B_output, B_direct,
      control, WpT, WoT, WdiT, Mpow + 16384, ctrlT);

  // proj = ctrlT @ WpT^T  (M=512,N=1024,K=512) -> bf16
  mfma_gemm_kernel<0, 1><<<dim3(8, 4, 8), 256, 0, stream>>>(
      ctrlT, WpT, nullptr, 0, proj, 512, 1024, 512);

  // projD = proj @ WdiT^T  (M=512,N=1152,K=1024) -> f32
  mfma_gemm_kernel<0, 0><<<dim3(9, 4, 8), 256, 0, stream>>>(
      proj, WdiT, nullptr, 0, projD, 512, 1152, 1024);

  // chunked scan
  powers_kernel<<<8, 256, 0, stream>>>(Mpow, 1);
  powers_kernel<<<16, 256, 0, stream>>>(Mpow, 2);
  powers_kernel<<<32, 256, 0, stream>>>(Mpow, 4);
  ec_kernel<<<512, 256, 0, stream>>>(Mpow, projD, Ec);
  combine_kernel<<<8, 128, 0, stream>>>(Mpow, Ec, Hc);
  pass2_kernel<<<512, 256, 0, stream>>>(Mpow, projD, Hc, S2);

  // YT = ((S2 @ WoT^T + direct) * win)^T  (M=512,N=1024,K=128) -> bf16 [N][M]
  mfma_gemm_kernel<1, 2><<<dim3(8, 4, 8), 256, 0, stream>>>(
      S2, WoT, projD, 1152, YT, 512, 1024, 128);

  // OLA: sigT[r][p] = YT[r][p] + YT[512+r][p-1]
  ola_kernel<<<2048, 256, 0, stream>>>(YT, sigT);

  // conv: softmax + Toeplitz-A on the fly + triangular MFMA GEMM -> out
  conv_mfma_kernel<<<dim3(4, 4, 8), 256, 0, stream>>>(times, sigT, out);
}